// Round 2
// baseline (159.746 us; speedup 1.0000x reference)
//
#include <hip/hip_runtime.h>
#include <hip/hip_bf16.h>
#include <hip/hip_fp16.h>

// SpMM: out[r] = sum_e (rows[e]==r) vals[e] * x[cols[e], :]
// rows sorted ascending (CSR-like). N=100000, E=1600000, D=48.
//
// R10: L2-resident feature-split int8.
//   Two passes over edges, 24 features each. Per-pass gather row:
//   24 x i8 + f32 scale + 4 pad = 32 B -> per-pass footprint 3.2 MB,
//   UNDER the 4 MB per-XCD L2 (first config that fits; R7's fp16 split
//   was 4.8 MB/pass -> still thrashed, hence its regression).
//   cols/vals/x loads are nontemporal so the 12.8 MB/pass edge stream
//   does not evict the resident xq. Per-half row scales (free accuracy).
// History:
//  - R9 int8 64 B rows single pass: 117.9 us, absmax 0.125. Footprint
//    6.4 MB > 4 MB L2 -> ~62% hit, spmm ~27 us of ~33 us controllable.
//  - R4/R5 pad fp16 rows to 128 B: REGRESSED (grew footprint).
//  - R7 fp16 feature-split + XCD pinning: REGRESSED (4.8 MB/pass still
//    > 4 MB; paid doubled edge stream without the hit-rate cliff).
//  - fp8 rejected on error budget; int4 rejected (~1.3 predicted absmax).

#define D_FEAT 48
#define HF 24           // features per pass
#define ROWB_H 32       // half-row: 24 q + 4 scale + 4 pad
#define TPR 12          // convert: threads per row
#define RPB 16          // convert: rows per block
#define TPR_H 6         // spmm: threads per row (4 features each)
#define RPB_H 32        // spmm: rows per block
#define BLOCK 192

typedef float vfloat4 __attribute__((ext_vector_type(4)));

__global__ void build_row_ptr_scatter(const int* __restrict__ rows,
                                      int* __restrict__ row_ptr,
                                      int n_edges, int n_nodes) {
    int e = blockIdx.x * blockDim.x + threadIdx.x;
    if (e >= n_edges) return;
    const int r     = rows[e];
    const int rprev = (e == 0) ? -1 : rows[e - 1];
    for (int q = rprev + 1; q <= r; ++q) row_ptr[q] = e;
    if (e == n_edges - 1) {
        for (int q = r + 1; q <= n_nodes; ++q) row_ptr[q] = n_edges;
    }
}

// Quantize x rows into two 32 B int8 half-rows with per-half scales.
__global__ __launch_bounds__(BLOCK) void convert_x_i8_split(
        const float* __restrict__ x,
        unsigned char* __restrict__ xqA,
        unsigned char* __restrict__ xqB, int n_nodes) {
    __shared__ float smax[RPB][TPR];
    const int tid = threadIdx.x;
    const int fg  = tid % TPR;          // 0..11, owns 4 features
    const int rib = tid / TPR;
    const int r   = blockIdx.x * RPB + rib;

    vfloat4 f = (vfloat4)(0.f);
    if (r < n_nodes)
        f = __builtin_nontemporal_load(
              reinterpret_cast<const vfloat4*>(x) + (size_t)r * TPR + fg);

    smax[rib][fg] = fmaxf(fmaxf(fabsf(f.x), fabsf(f.y)),
                          fmaxf(fabsf(f.z), fabsf(f.w)));
    __syncthreads();

    const int hbase = (fg < 6) ? 0 : 6;  // which half this thread belongs to
    float hmax = 0.f;
#pragma unroll
    for (int i = 0; i < 6; ++i) hmax = fmaxf(hmax, smax[rib][hbase + i]);
    if (r >= n_nodes) return;

    const float inv = (hmax > 0.f) ? (127.0f / hmax) : 0.f;

    union { signed char c[4]; unsigned int u; } pk;
    pk.c[0] = (signed char)(int)rintf(fminf(fmaxf(f.x * inv, -127.f), 127.f));
    pk.c[1] = (signed char)(int)rintf(fminf(fmaxf(f.y * inv, -127.f), 127.f));
    pk.c[2] = (signed char)(int)rintf(fminf(fmaxf(f.z * inv, -127.f), 127.f));
    pk.c[3] = (signed char)(int)rintf(fminf(fmaxf(f.w * inv, -127.f), 127.f));

    unsigned char* half = (fg < 6) ? xqA : xqB;
    const int      off  = (fg < 6) ? fg * 4 : (fg - 6) * 4;
    *reinterpret_cast<unsigned int*>(half + (size_t)r * ROWB_H + off) = pk.u;
    if (fg == 0) *reinterpret_cast<float*>(xqA + (size_t)r * ROWB_H + 24) = hmax * (1.0f / 127.0f);
    if (fg == 6) *reinterpret_cast<float*>(xqB + (size_t)r * ROWB_H + 24) = hmax * (1.0f / 127.0f);
}

__device__ __forceinline__ void fma4_q(vfloat4& acc, float vs, unsigned int q) {
    acc.x += vs * (float)(int)(signed char)(q & 0xffu);
    acc.y += vs * (float)(int)(signed char)((q >> 8) & 0xffu);
    acc.z += vs * (float)(int)(signed char)((q >> 16) & 0xffu);
    acc.w += vs * (float)(int)(signed char)(q >> 24);
}

// One feature-half pass: gather 32 B rows that are fully L2-resident.
__global__ __launch_bounds__(BLOCK) void spmm_rows_i8h(
        const int* __restrict__ row_ptr,
        const int* __restrict__ cols,
        const float* __restrict__ vals,
        const unsigned char* __restrict__ xq,
        float* __restrict__ out,        // pre-offset to this half's base
        int n_nodes) {
    const int tid = threadIdx.x;
    const int fg  = tid % TPR_H;        // 0..5, owns 4 features
    const int rib = tid / TPR_H;        // 0..31
    const int r   = blockIdx.x * RPB_H + rib;
    if (r >= n_nodes) return;

    const int e0 = row_ptr[r];
    const int e1 = row_ptr[r + 1];

    vfloat4 acc = (vfloat4)(0.f);

    int e = e0;
    // 8-edge unroll: 16 independent gather chains (q + scale) in flight.
    // cols/vals are nontemporal: streaming, must not evict resident xq.
    for (; e + 7 < e1; e += 8) {
        int   c[8];
        float v[8];
#pragma unroll
        for (int j = 0; j < 8; ++j) {
            c[j] = __builtin_nontemporal_load(cols + e + j);
            v[j] = __builtin_nontemporal_load(vals + e + j);
        }
        unsigned int q[8];
        float        s[8];
#pragma unroll
        for (int j = 0; j < 8; ++j) {
            const unsigned char* row = xq + (size_t)c[j] * ROWB_H;
            q[j] = *reinterpret_cast<const unsigned int*>(row + fg * 4);
            s[j] = *reinterpret_cast<const float*>(row + 24);
        }
#pragma unroll
        for (int j = 0; j < 8; ++j) fma4_q(acc, v[j] * s[j], q[j]);
    }
    for (; e + 3 < e1; e += 4) {
        int   c[4];
        float v[4];
#pragma unroll
        for (int j = 0; j < 4; ++j) {
            c[j] = __builtin_nontemporal_load(cols + e + j);
            v[j] = __builtin_nontemporal_load(vals + e + j);
        }
        unsigned int q[4];
        float        s[4];
#pragma unroll
        for (int j = 0; j < 4; ++j) {
            const unsigned char* row = xq + (size_t)c[j] * ROWB_H;
            q[j] = *reinterpret_cast<const unsigned int*>(row + fg * 4);
            s[j] = *reinterpret_cast<const float*>(row + 24);
        }
#pragma unroll
        for (int j = 0; j < 4; ++j) fma4_q(acc, v[j] * s[j], q[j]);
    }
    for (; e < e1; ++e) {
        const unsigned char* row = xq + (size_t)__builtin_nontemporal_load(cols + e) * ROWB_H;
        const unsigned int  q = *reinterpret_cast<const unsigned int*>(row + fg * 4);
        const float         s = *reinterpret_cast<const float*>(row + 24);
        fma4_q(acc, __builtin_nontemporal_load(vals + e) * s, q);
    }

    __builtin_nontemporal_store(acc,
        reinterpret_cast<vfloat4*>(out + (size_t)r * D_FEAT + fg * 4));
}

// f32 fallback (used only if ws_size can't hold the quantized copies)
__global__ __launch_bounds__(BLOCK) void spmm_rows_f32(
        const int* __restrict__ row_ptr,
        const int* __restrict__ cols,
        const float* __restrict__ vals,
        const float* __restrict__ x,
        float* __restrict__ out,
        int n_nodes) {
    const int tid = threadIdx.x;
    const int fg  = tid % TPR;
    const int rib = tid / TPR;
    const int r   = blockIdx.x * RPB + rib;
    if (r >= n_nodes) return;
    const int e0 = row_ptr[r];
    const int e1 = row_ptr[r + 1];
    float4 acc = make_float4(0.f, 0.f, 0.f, 0.f);
    for (int e = e0; e < e1; ++e) {
        const float v = vals[e];
        const float4 xa = *reinterpret_cast<const float4*>(
            x + (size_t)cols[e] * D_FEAT + fg * 4);
        acc.x += v * xa.x; acc.y += v * xa.y;
        acc.z += v * xa.z; acc.w += v * xa.w;
    }
    *reinterpret_cast<float4*>(out + (size_t)r * D_FEAT + fg * 4) = acc;
}

extern "C" void kernel_launch(void* const* d_in, const int* in_sizes, int n_in,
                              void* d_out, int out_size, void* d_ws, size_t ws_size,
                              hipStream_t stream) {
    // inputs: t(f32,1), x(f32,N*48), rows(i32,E), cols(i32,E), vals(f32,E)
    const float* x    = (const float*)d_in[1];
    const int*   rows = (const int*)  d_in[2];
    const int*   cols = (const int*)  d_in[3];
    const float* vals = (const float*)d_in[4];
    float*       out  = (float*)d_out;

    const int n_edges = in_sizes[2];
    const int n_nodes = out_size / D_FEAT;     // 100000

    int* row_ptr = (int*)d_ws;                 // (n_nodes+1) ints
    const size_t rp_bytes = (size_t)(n_nodes + 1) * sizeof(int);
    const size_t xa_off   = (rp_bytes + 255) & ~(size_t)255;
    const size_t xb_off   = xa_off + (size_t)n_nodes * ROWB_H;
    const size_t need     = xb_off + (size_t)n_nodes * ROWB_H;

    {
        const int threads = 256;
        const int grid = (n_edges + threads - 1) / threads;
        build_row_ptr_scatter<<<grid, threads, 0, stream>>>(rows, row_ptr, n_edges, n_nodes);
    }

    if (ws_size >= need) {
        unsigned char* xqA = (unsigned char*)d_ws + xa_off;
        unsigned char* xqB = (unsigned char*)d_ws + xb_off;
        {
            const int grid = (n_nodes + RPB - 1) / RPB;
            convert_x_i8_split<<<grid, BLOCK, 0, stream>>>(x, xqA, xqB, n_nodes);
        }
        const int grid = (n_nodes + RPB_H - 1) / RPB_H;
        // Two sequential passes so only ONE 3.2 MB half is hot at a time.
        spmm_rows_i8h<<<grid, BLOCK, 0, stream>>>(row_ptr, cols, vals, xqA, out,      n_nodes);
        spmm_rows_i8h<<<grid, BLOCK, 0, stream>>>(row_ptr, cols, vals, xqB, out + HF, n_nodes);
    } else {
        const int grid = (n_nodes + RPB - 1) / RPB;
        spmm_rows_f32<<<grid, BLOCK, 0, stream>>>(row_ptr, cols, vals, x, out, n_nodes);
    }
}

// Round 4
// 122.930 us; speedup vs baseline: 1.2995x; 1.2995x over previous
//
#include <hip/hip_runtime.h>
#include <hip/hip_bf16.h>
#include <hip/hip_fp16.h>

// SpMM: out[r] = sum_e (rows[e]==r) vals[e] * x[cols[e], :]
// rows sorted ascending (CSR-like). N=100000, E=1600000, D=48.
//
// R12 == R11 resubmitted (previous bench died on container acquisition,
// no measurement was taken; kernel uses no forbidden APIs and ws fits).
//
// R11: R9 structure (measured best, 117.9 us) + scale folded into vals.
//   sv[e] = vals[e] * scale[cols[e]] precomputed in an E-parallel pre-pass
//   fused with the row_ptr scatter (scale gathers hit a 400 KB L2-resident
//   table). The spmm then issues exactly ONE gather request per edge
//   (the 64 B int8 row), down from two (row + per-edge scale broadcast).
// Evidence driving this: R10's feature-split halved miss BYTES (3.2 MB
//   L2-resident halves) yet ran ~2x slower per byte -> the spmm is bound
//   by gather REQUEST throughput / latency x parallelism, not bytes.
//   (R9: ~3.2M requests in ~27 us ~ 280 req/cy chip-wide, saturated.)
// History:
//  - R10 two-pass 32 B rows, TPR 6: REGRESSED 159.7 (requests unchanged
//    x2 passes, threads halved; byte savings bought nothing).
//  - R9 int8 64 B rows single pass: BEST 117.9 us, absmax 0.125.
//  - R4/R5 pad fp16 rows to 128 B: REGRESSED (grew footprint).
//  - R7 fp16 feature-split + XCD pinning: REGRESSED.
//  - fp8 / int4 rejected on error budget (~1.0 / ~1.3 predicted absmax).

#define D_FEAT 48
#define TPR 12          // threads per row (each owns a 4-feature slice)
#define RPB 16          // rows per block
#define BLOCK (TPR * RPB)  // 192
#define ROW_BYTES 64    // int8 row: 48 q + 16 pad (scale lives in scale_tbl)

typedef float vfloat4 __attribute__((ext_vector_type(4)));

// Quantize x rows to int8 with per-row scale; scale goes to a compact
// 400 KB table (L2-resident for the pre-pass gathers).
__global__ __launch_bounds__(BLOCK) void convert_x_i8(
        const float* __restrict__ x,
        unsigned char* __restrict__ xq,
        float* __restrict__ scale_tbl, int n_nodes) {
    __shared__ float smax[RPB][TPR];
    const int tid = threadIdx.x;
    const int fg  = tid % TPR;
    const int rib = tid / TPR;
    const int r   = blockIdx.x * RPB + rib;

    float4 f = make_float4(0.f, 0.f, 0.f, 0.f);
    if (r < n_nodes)
        f = reinterpret_cast<const float4*>(x)[(size_t)r * (D_FEAT / 4) + fg];

    smax[rib][fg] = fmaxf(fmaxf(fabsf(f.x), fabsf(f.y)),
                          fmaxf(fabsf(f.z), fabsf(f.w)));
    __syncthreads();

    float rmax = 0.f;
#pragma unroll
    for (int i = 0; i < TPR; ++i) rmax = fmaxf(rmax, smax[rib][i]);
    if (r >= n_nodes) return;

    const float inv = (rmax > 0.f) ? (127.0f / rmax) : 0.f;

    union { signed char c[4]; unsigned int u; } pk;
    pk.c[0] = (signed char)(int)rintf(fminf(fmaxf(f.x * inv, -127.f), 127.f));
    pk.c[1] = (signed char)(int)rintf(fminf(fmaxf(f.y * inv, -127.f), 127.f));
    pk.c[2] = (signed char)(int)rintf(fminf(fmaxf(f.z * inv, -127.f), 127.f));
    pk.c[3] = (signed char)(int)rintf(fminf(fmaxf(f.w * inv, -127.f), 127.f));

    *reinterpret_cast<unsigned int*>(
        xq + (size_t)r * ROW_BYTES + fg * 4) = pk.u;
    if (fg == 0) scale_tbl[r] = rmax * (1.0f / 127.0f);
}

// Fused E-parallel pre-pass: row_ptr scatter + sv = vals * scale[cols].
// Scale gathers hit the 400 KB table -> L2-resident, fully overlapped.
__global__ void prep_edges(const int* __restrict__ rows,
                           const int* __restrict__ cols,
                           const float* __restrict__ vals,
                           const float* __restrict__ scale_tbl,
                           int* __restrict__ row_ptr,
                           float* __restrict__ sv,
                           int n_edges, int n_nodes) {
    int e = blockIdx.x * blockDim.x + threadIdx.x;
    if (e >= n_edges) return;
    const int r     = rows[e];
    const int rprev = (e == 0) ? -1 : rows[e - 1];
    for (int q = rprev + 1; q <= r; ++q) row_ptr[q] = e;
    if (e == n_edges - 1) {
        for (int q = r + 1; q <= n_nodes; ++q) row_ptr[q] = n_edges;
    }
    sv[e] = vals[e] * scale_tbl[cols[e]];
}

__device__ __forceinline__ void fma4_q(vfloat4& acc, float vs, unsigned int q) {
    acc.x += vs * (float)(int)(signed char)(q & 0xffu);
    acc.y += vs * (float)(int)(signed char)((q >> 8) & 0xffu);
    acc.z += vs * (float)(int)(signed char)((q >> 16) & 0xffu);
    acc.w += vs * (float)(int)(signed char)(q >> 24);
}

// One gather request per edge: the 64 B int8 row. sv is streamed.
__global__ __launch_bounds__(BLOCK) void spmm_rows_i8(
        const int* __restrict__ row_ptr,
        const int* __restrict__ cols,
        const float* __restrict__ sv,
        const unsigned char* __restrict__ xq,
        float* __restrict__ out,
        int n_nodes) {
    const int tid = threadIdx.x;
    const int fg  = tid % TPR;
    const int rib = tid / TPR;
    const int r   = blockIdx.x * RPB + rib;
    if (r >= n_nodes) return;

    const int e0 = row_ptr[r];
    const int e1 = row_ptr[r + 1];

    vfloat4 acc = (vfloat4)(0.f);

    int e = e0;
    // 8-edge unroll: eight independent gather chains in flight per thread.
    for (; e + 7 < e1; e += 8) {
        int   c[8];
        float v[8];
#pragma unroll
        for (int j = 0; j < 8; ++j) { c[j] = cols[e + j]; v[j] = sv[e + j]; }
        unsigned int q[8];
#pragma unroll
        for (int j = 0; j < 8; ++j)
            q[j] = *reinterpret_cast<const unsigned int*>(
                       xq + (size_t)c[j] * ROW_BYTES + fg * 4);
#pragma unroll
        for (int j = 0; j < 8; ++j) fma4_q(acc, v[j], q[j]);
    }
    for (; e + 3 < e1; e += 4) {
        int   c[4];
        float v[4];
#pragma unroll
        for (int j = 0; j < 4; ++j) { c[j] = cols[e + j]; v[j] = sv[e + j]; }
        unsigned int q[4];
#pragma unroll
        for (int j = 0; j < 4; ++j)
            q[j] = *reinterpret_cast<const unsigned int*>(
                       xq + (size_t)c[j] * ROW_BYTES + fg * 4);
#pragma unroll
        for (int j = 0; j < 4; ++j) fma4_q(acc, v[j], q[j]);
    }
    for (; e < e1; ++e) {
        const unsigned int q = *reinterpret_cast<const unsigned int*>(
            xq + (size_t)cols[e] * ROW_BYTES + fg * 4);
        fma4_q(acc, sv[e], q);
    }

    __builtin_nontemporal_store(acc,
        reinterpret_cast<vfloat4*>(out + (size_t)r * D_FEAT + fg * 4));
}

// f32 fallback (used only if ws_size can't hold the quantized copy)
__global__ void build_row_ptr_scatter(const int* __restrict__ rows,
                                      int* __restrict__ row_ptr,
                                      int n_edges, int n_nodes) {
    int e = blockIdx.x * blockDim.x + threadIdx.x;
    if (e >= n_edges) return;
    const int r     = rows[e];
    const int rprev = (e == 0) ? -1 : rows[e - 1];
    for (int q = rprev + 1; q <= r; ++q) row_ptr[q] = e;
    if (e == n_edges - 1) {
        for (int q = r + 1; q <= n_nodes; ++q) row_ptr[q] = n_edges;
    }
}

__global__ __launch_bounds__(BLOCK) void spmm_rows_f32(
        const int* __restrict__ row_ptr,
        const int* __restrict__ cols,
        const float* __restrict__ vals,
        const float* __restrict__ x,
        float* __restrict__ out,
        int n_nodes) {
    const int tid = threadIdx.x;
    const int fg  = tid % TPR;
    const int rib = tid / TPR;
    const int r   = blockIdx.x * RPB + rib;
    if (r >= n_nodes) return;
    const int e0 = row_ptr[r];
    const int e1 = row_ptr[r + 1];
    float4 acc = make_float4(0.f, 0.f, 0.f, 0.f);
    for (int e = e0; e < e1; ++e) {
        const float v = vals[e];
        const float4 xa = *reinterpret_cast<const float4*>(
            x + (size_t)cols[e] * D_FEAT + fg * 4);
        acc.x += v * xa.x; acc.y += v * xa.y;
        acc.z += v * xa.z; acc.w += v * xa.w;
    }
    *reinterpret_cast<float4*>(out + (size_t)r * D_FEAT + fg * 4) = acc;
}

extern "C" void kernel_launch(void* const* d_in, const int* in_sizes, int n_in,
                              void* d_out, int out_size, void* d_ws, size_t ws_size,
                              hipStream_t stream) {
    // inputs: t(f32,1), x(f32,N*48), rows(i32,E), cols(i32,E), vals(f32,E)
    const float* x    = (const float*)d_in[1];
    const int*   rows = (const int*)  d_in[2];
    const int*   cols = (const int*)  d_in[3];
    const float* vals = (const float*)d_in[4];
    float*       out  = (float*)d_out;

    const int n_edges = in_sizes[2];
    const int n_nodes = out_size / D_FEAT;     // 100000

    int* row_ptr = (int*)d_ws;                 // (n_nodes+1) ints
    const size_t rp_bytes = (size_t)(n_nodes + 1) * sizeof(int);
    const size_t xq_off   = (rp_bytes + 255) & ~(size_t)255;
    const size_t st_off   = xq_off + (size_t)n_nodes * ROW_BYTES;
    const size_t sv_off   = (st_off + (size_t)n_nodes * sizeof(float) + 255) & ~(size_t)255;
    const size_t need     = sv_off + (size_t)n_edges * sizeof(float);

    if (ws_size >= need) {
        unsigned char* xq        = (unsigned char*)d_ws + xq_off;
        float*         scale_tbl = (float*)((char*)d_ws + st_off);
        float*         sv        = (float*)((char*)d_ws + sv_off);
        {
            const int grid = (n_nodes + RPB - 1) / RPB;
            convert_x_i8<<<grid, BLOCK, 0, stream>>>(x, xq, scale_tbl, n_nodes);
        }
        {
            const int threads = 256;
            const int grid = (n_edges + threads - 1) / threads;
            prep_edges<<<grid, threads, 0, stream>>>(rows, cols, vals, scale_tbl,
                                                     row_ptr, sv, n_edges, n_nodes);
        }
        const int grid = (n_nodes + RPB - 1) / RPB;
        spmm_rows_i8<<<grid, BLOCK, 0, stream>>>(row_ptr, cols, sv, xq, out, n_nodes);
    } else {
        {
            const int threads = 256;
            const int grid = (n_edges + threads - 1) / threads;
            build_row_ptr_scatter<<<grid, threads, 0, stream>>>(rows, row_ptr, n_edges, n_nodes);
        }
        const int grid = (n_nodes + RPB - 1) / RPB;
        spmm_rows_f32<<<grid, BLOCK, 0, stream>>>(row_ptr, cols, vals, x, out, n_nodes);
    }
}